// Round 12
// baseline (153.240 us; speedup 1.0000x reference)
//
#include <hip/hip_runtime.h>
#include <math.h>

#define C 64
#define BN 128              // nodes per destination bucket
#define BSHIFT 7            // log2(BN)
#define NPART 512           // partition blocks
#define EPB_CAP 3200        // LDS staging capacity per partition block
#define SCAP 4096           // LDS staging capacity per sort bucket (mean 2046, ~45 sigma)
#define RMASK ((1 << 20) - 1)

typedef unsigned int uint;
typedef unsigned short ushort;

__device__ __forceinline__ float sigf(float x) { return 1.0f / (1.0f + __expf(-x)); }

// round-to-nearest-even f32 -> bf16 bits (values are finite, no NaN handling)
__device__ __forceinline__ ushort f2bf(float f) {
    uint u = __float_as_uint(f);
    return (ushort)((u + 0x7fffu + ((u >> 16) & 1u)) >> 16);
}

// fma 8 packed bf16 (uint4) into acc[8]
__device__ __forceinline__ void bf8fma(uint4 u, float nn, float* a) {
    a[0] = fmaf(__uint_as_float(u.x << 16),          nn, a[0]);
    a[1] = fmaf(__uint_as_float(u.x & 0xffff0000u),  nn, a[1]);
    a[2] = fmaf(__uint_as_float(u.y << 16),          nn, a[2]);
    a[3] = fmaf(__uint_as_float(u.y & 0xffff0000u),  nn, a[3]);
    a[4] = fmaf(__uint_as_float(u.z << 16),          nn, a[4]);
    a[5] = fmaf(__uint_as_float(u.z & 0xffff0000u),  nn, a[5]);
    a[6] = fmaf(__uint_as_float(u.w << 16),          nn, a[6]);
    a[7] = fmaf(__uint_as_float(u.w & 0xffff0000u),  nn, a[7]);
}

// ---- Kernel 1: hist (blocks < NPART) + LSTM weight (blocks >= NPART) ------
// Independent work fused into one grid; no cross-block communication.
__global__ __launch_bounds__(256) void hist_lstm_kernel(
    const int* __restrict__ col, int* __restrict__ hist,
    int E, int nbuck, int epb,
    const float* __restrict__ cw,
    const float* __restrict__ wf, const float* __restrict__ bif, const float* __restrict__ bhf,
    const float* __restrict__ wb, const float* __restrict__ bib, const float* __restrict__ bhb,
    float* __restrict__ W)
{
    int b = blockIdx.x, t = threadIdx.x;

    if (b >= NPART) {
        // ---- LSTM: W = max(lstm_fwd(conv_w), lstm_bwd(conv_w)) ----
        int tid = (b - NPART) * 256 + t;       // 0..4095
        int r = tid >> 6, c = tid & 63;
        const float* x = cw + r * C;
        const float* f_i = wf + (0 * C + c) * C;
        const float* f_g = wf + (2 * C + c) * C;
        const float* f_o = wf + (3 * C + c) * C;
        const float* b_i = wb + (0 * C + c) * C;
        const float* b_g = wb + (2 * C + c) * C;
        const float* b_o = wb + (3 * C + c) * C;

        float zif = 0.f, zgf = 0.f, zof = 0.f, zib = 0.f, zgb = 0.f, zob = 0.f;
        #pragma unroll
        for (int k = 0; k < C; ++k) {
            float xv = x[k];
            zif = fmaf(xv, f_i[k], zif);
            zgf = fmaf(xv, f_g[k], zgf);
            zof = fmaf(xv, f_o[k], zof);
            zib = fmaf(xv, b_i[k], zib);
            zgb = fmaf(xv, b_g[k], zgb);
            zob = fmaf(xv, b_o[k], zob);
        }
        zif += bif[0 * C + c] + bhf[0 * C + c];
        zgf += bif[2 * C + c] + bhf[2 * C + c];
        zof += bif[3 * C + c] + bhf[3 * C + c];
        zib += bib[0 * C + c] + bhb[0 * C + c];
        zgb += bib[2 * C + c] + bhb[2 * C + c];
        zob += bib[3 * C + c] + bhb[3 * C + c];

        float cf = sigf(zif) * tanhf(zgf);
        float hf = sigf(zof) * tanhf(cf);
        float cb = sigf(zib) * tanhf(zgb);
        float hb = sigf(zob) * tanhf(cb);
        W[tid] = fmaxf(hf, hb);
        return;
    }

    __shared__ int h[1024];
    for (int i = t; i < nbuck; i += 256) h[i] = 0;
    __syncthreads();
    int base = b * epb;
    int end = min(base + epb, E);
    for (int e = base + t; e < end; e += 256)
        atomicAdd(&h[col[e] >> BSHIFT], 1);
    __syncthreads();
    for (int i = t; i < nbuck; i += 256) hist[b * nbuck + i] = h[i];
}

// ---- Kernel 2: per-bucket exclusive scan over blocks (parallel) -----------
// One block per bucket k: NPART threads scan hist[b][k] over b.
// Writes per-bucket TOTAL to btot[k] (spine scan done by consumers in-LDS).
__global__ __launch_bounds__(512) void scan_blocks_kernel(
    int* __restrict__ hist, int* __restrict__ btot, int nbuck)
{
    __shared__ int wsum[8];
    int k = blockIdx.x;
    int b = threadIdx.x;
    int v = hist[b * nbuck + k];
    int lane = b & 63, wid = b >> 6;
    int x = v;
    #pragma unroll
    for (int d = 1; d < 64; d <<= 1) {
        int y = __shfl_up(x, d, 64);
        if (lane >= d) x += y;
    }
    if (lane == 63) wsum[wid] = x;
    __syncthreads();
    if (b == 0) {
        int run = 0;
        #pragma unroll
        for (int w = 0; w < 8; ++w) { int z = wsum[w]; wsum[w] = run; run += z; }
    }
    __syncthreads();
    int excl = x - v + wsum[wid];
    hist[b * nbuck + k] = excl;
    if (b == NPART - 1) btot[k] = excl + v;
}

// ---- Kernel 3: partition — in-LDS spine + LDS counting sort, coalesced out
__global__ __launch_bounds__(512) void partition_kernel(
    const int* __restrict__ row, const int* __restrict__ col,
    const float* __restrict__ ew, const int* __restrict__ hist,
    const int* __restrict__ btot, int2* __restrict__ payload,
    int E, int nbuck, int epb)
{
    __shared__ int bins[1024];
    __shared__ int base[1024];
    __shared__ int cur[1024];
    __shared__ int hbase[1024];
    __shared__ int bbl[1024];
    __shared__ int2 lpay[EPB_CAP];      // 25.6 KB
    __shared__ ushort karr[EPB_CAP];    // 6.4 KB
    __shared__ int wsum[8];

    int t = threadIdx.x, b = blockIdx.x;
    int lane = t & 63, wid = t >> 6;

    // ---- in-LDS spine: bbl = exclusive scan of btot[0..nbuck-1] ----
    {
        int i0 = 2 * t, i1 = 2 * t + 1;
        int v0 = (i0 < nbuck) ? btot[i0] : 0;
        int v1 = (i1 < nbuck) ? btot[i1] : 0;
        int s = v0 + v1;
        int x = s;
        #pragma unroll
        for (int d = 1; d < 64; d <<= 1) {
            int y = __shfl_up(x, d, 64);
            if (lane >= d) x += y;
        }
        if (lane == 63) wsum[wid] = x;
        __syncthreads();
        if (t == 0) {
            int run = 0;
            #pragma unroll
            for (int w = 0; w < 8; ++w) { int z = wsum[w]; wsum[w] = run; run += z; }
        }
        __syncthreads();
        int excl = x - s + wsum[wid];
        bbl[i0] = excl;
        bbl[i1] = excl + v0;
    }

    for (int i = t; i < 1024; i += 512) {
        bins[i] = 0;
        hbase[i] = (i < nbuck) ? hist[b * nbuck + i] : 0;
    }
    __syncthreads();

    int e0 = b * epb;
    int e1 = min(e0 + epb, E);
    for (int e = e0 + t; e < e1; e += 512)
        atomicAdd(&bins[col[e] >> BSHIFT], 1);
    __syncthreads();

    {
        int a = bins[2 * t], b2 = bins[2 * t + 1];
        int s = a + b2;
        int x = s;
        #pragma unroll
        for (int d = 1; d < 64; d <<= 1) {
            int y = __shfl_up(x, d, 64);
            if (lane >= d) x += y;
        }
        if (lane == 63) wsum[wid] = x;
        __syncthreads();
        if (t == 0) {
            int run = 0;
            #pragma unroll
            for (int w = 0; w < 8; ++w) { int z = wsum[w]; wsum[w] = run; run += z; }
        }
        __syncthreads();
        int excl = x - s + wsum[wid];
        base[2 * t] = excl;
        base[2 * t + 1] = excl + a;
        cur[2 * t] = excl;
        cur[2 * t + 1] = excl + a;
    }
    __syncthreads();

    for (int e = e0 + t; e < e1; e += 512) {
        int c = col[e];
        int k = c >> BSHIFT;
        int pos = atomicAdd(&cur[k], 1);
        lpay[pos] = make_int2(row[e] | ((c & (BN - 1)) << 20),
                              __float_as_int(ew[e]));
        karr[pos] = (ushort)k;
    }
    __syncthreads();

    int tot = e1 - e0;
    for (int i = t; i < tot; i += 512) {
        int k = karr[i];
        int dst = bbl[k] + hbase[k] + (i - base[k]);
        payload[dst] = lpay[i];
    }
}

// ---- Kernel 4: sort_bucket — in-LDS spine + LDS-staged counting sort ------
__global__ __launch_bounds__(512) void sort_bucket_kernel(
    const int2* __restrict__ payload, const int* __restrict__ btot,
    int2* __restrict__ payload2, float* __restrict__ dinv,
    int2* __restrict__ seg, int N, int nbuck)
{
    __shared__ int bin[BN];
    __shared__ int bbase[BN];
    __shared__ int cur[BN];
    __shared__ float degl[BN];
    __shared__ float dinvl[BN];
    __shared__ int bbl[1024];
    __shared__ int2 spay[SCAP];         // 32 KB
    __shared__ int wsum[8];
    int t = threadIdx.x, k = blockIdx.x;
    int lane = t & 63, wid = t >> 6;

    // ---- in-LDS spine: bbl = exclusive scan of btot[0..nbuck-1] ----
    {
        int i0 = 2 * t, i1 = 2 * t + 1;
        int v0 = (i0 < nbuck) ? btot[i0] : 0;
        int v1 = (i1 < nbuck) ? btot[i1] : 0;
        int s = v0 + v1;
        int x = s;
        #pragma unroll
        for (int d = 1; d < 64; d <<= 1) {
            int y = __shfl_up(x, d, 64);
            if (lane >= d) x += y;
        }
        if (lane == 63) wsum[wid] = x;
        __syncthreads();
        if (t == 0) {
            int run = 0;
            #pragma unroll
            for (int w = 0; w < 8; ++w) { int z = wsum[w]; wsum[w] = run; run += z; }
        }
        __syncthreads();
        int excl = x - s + wsum[wid];
        bbl[i0] = excl;
        bbl[i1] = excl + v0;
    }
    if (t < BN) { bin[t] = 0; degl[t] = 0.f; }
    __syncthreads();

    int e0 = bbl[k], e1 = e0 + btot[k];
    for (int e = e0 + t; e < e1; e += 512) {
        int2 p = payload[e];
        int ld = p.x >> 20;
        atomicAdd(&bin[ld], 1);
        atomicAdd(&degl[ld], __int_as_float(p.y));
    }
    __syncthreads();

    // exclusive scan of bin[0..127] in wave 0 (2 bins per lane)
    if (t < 64) {
        int a = bin[2 * t], b2 = bin[2 * t + 1];
        int s = a + b2;
        int x = s;
        #pragma unroll
        for (int d = 1; d < 64; d <<= 1) {
            int y = __shfl_up(x, d, 64);
            if (t >= d) x += y;
        }
        int excl = x - s;
        bbase[2 * t] = excl;
        bbase[2 * t + 1] = excl + a;
    }
    __syncthreads();

    if (t < BN) {
        int n = k * BN + t;
        float di = rsqrtf(degl[t] + 1.0f);    // +1 self-loop weight
        dinvl[t] = di;
        cur[t] = bbase[t];                    // 0-based local cursor
        if (n < N) {
            dinv[n] = di;
            seg[n] = make_int2(e0 + bbase[t], bin[t]);
        }
    }
    __syncthreads();

    int tot = e1 - e0;
    if (tot <= SCAP) {
        // scatter into LDS (payload re-read is L2-hot), then coalesced write
        for (int e = e0 + t; e < e1; e += 512) {
            int2 p = payload[e];
            int ld = p.x >> 20;
            int pos = atomicAdd(&cur[ld], 1);
            spay[pos] = make_int2(p.x & RMASK,
                                  __float_as_int(__int_as_float(p.y) * dinvl[ld]));
        }
        __syncthreads();
        for (int i = t; i < tot; i += 512)
            payload2[e0 + i] = spay[i];
    } else {
        // fallback: direct global scatter (never expected for this data)
        for (int e = e0 + t; e < e1; e += 512) {
            int2 p = payload[e];
            int ld = p.x >> 20;
            int pos = atomicAdd(&cur[ld], 1);
            payload2[e0 + pos] = make_int2(p.x & RMASK,
                                           __float_as_int(__int_as_float(p.y) * dinvl[ld]));
        }
    }
}

// ---- Kernel 5: Xw' = bf16( dinv ⊙ (X @ W) )  (64 rows/block, 512 thr) -----
__global__ __launch_bounds__(512) void gemm_xw_kernel(
    const float* __restrict__ X, const float* __restrict__ W,
    const float* __restrict__ dinv, ushort* __restrict__ Y, int N)
{
    __shared__ float Wl[C * C];         // 16 KB
    __shared__ float xl[64][C];         // 16 KB
    int t = threadIdx.x;
    #pragma unroll
    for (int i = 0; i < 2; ++i)
        *(float4*)(Wl + 4 * (t + i * 512)) = *(const float4*)(W + 4 * (t + i * 512));

    int n0 = blockIdx.x * 64;
    #pragma unroll
    for (int i = 0; i < 2; ++i) {
        int idx = t + i * 512;            // 0..1023 : (row, float4-group)
        int rr = idx >> 4, cc = (idx & 15) << 2;
        int n = n0 + rr;
        float4 v = (n < N) ? *(const float4*)(X + (size_t)n * C + cc)
                           : make_float4(0.f, 0.f, 0.f, 0.f);
        *(float4*)(&xl[rr][cc]) = v;
    }
    __syncthreads();

    int c = t & 63, rb = (t >> 6) * 8;    // 8 waves x 8 rows = 64 rows
    float acc[8] = {0.f, 0.f, 0.f, 0.f, 0.f, 0.f, 0.f, 0.f};
    for (int k = 0; k < C; ++k) {
        float w = Wl[k * C + c];
        #pragma unroll
        for (int q = 0; q < 8; ++q) acc[q] = fmaf(xl[rb + q][k], w, acc[q]);
    }
    #pragma unroll
    for (int q = 0; q < 8; ++q) {
        int n = n0 + rb + q;
        if (n < N) Y[(size_t)n * C + c] = f2bf(acc[q] * dinv[n]);  // fold dinv[src]
    }
}

// ---- Kernel 6: gather-reduce, 8 lanes/node, uint4 gathers, 4 edges in flight
// tmp[n] = bf16( ne + ce + dinv[n]*Xw'[n] + sum_seg pn * Xw'[src] )
__global__ __launch_bounds__(256) void reduce_kernel(
    const int2* __restrict__ seg, const int2* __restrict__ payload2,
    const ushort* __restrict__ Xw, const float* __restrict__ dinv,
    const float* __restrict__ ne, const float* __restrict__ ce,
    ushort* __restrict__ tmpb, int N)
{
    int t = blockIdx.x * 256 + threadIdx.x;
    int n = t >> 3;
    if (n >= N) return;
    int cs = (t & 7) << 3;                 // channel offset (8 channels/lane)

    int2 s = seg[n];
    int p = s.x, cnt = s.y;
    float a[8] = {0.f, 0.f, 0.f, 0.f, 0.f, 0.f, 0.f, 0.f};
    while (cnt >= 4) {
        int2 p0 = payload2[p];
        int2 p1 = payload2[p + 1];
        int2 p2 = payload2[p + 2];
        int2 p3 = payload2[p + 3];
        uint4 u0 = *(const uint4*)(Xw + (size_t)p0.x * C + cs);
        uint4 u1 = *(const uint4*)(Xw + (size_t)p1.x * C + cs);
        uint4 u2 = *(const uint4*)(Xw + (size_t)p2.x * C + cs);
        uint4 u3 = *(const uint4*)(Xw + (size_t)p3.x * C + cs);
        bf8fma(u0, __int_as_float(p0.y), a);
        bf8fma(u1, __int_as_float(p1.y), a);
        bf8fma(u2, __int_as_float(p2.y), a);
        bf8fma(u3, __int_as_float(p3.y), a);
        p += 4; cnt -= 4;
    }
    while (cnt > 0) {
        int2 pl = payload2[p];
        uint4 u = *(const uint4*)(Xw + (size_t)pl.x * C + cs);
        bf8fma(u, __int_as_float(pl.y), a);
        ++p; --cnt;
    }
    float di = dinv[n];
    size_t o = (size_t)n * C + cs;
    uint4 ux = *(const uint4*)(Xw + o);     // Xw' = dinv[n]*(X@W)[n]
    bf8fma(ux, di, a);
    const float4 nv0 = *(const float4*)(ne + o);
    const float4 nv1 = *(const float4*)(ne + o + 4);
    const float4 cv0 = *(const float4*)(ce + o);
    const float4 cv1 = *(const float4*)(ce + o + 4);
    a[0] += nv0.x + cv0.x;  a[1] += nv0.y + cv0.y;
    a[2] += nv0.z + cv0.z;  a[3] += nv0.w + cv0.w;
    a[4] += nv1.x + cv1.x;  a[5] += nv1.y + cv1.y;
    a[6] += nv1.z + cv1.z;  a[7] += nv1.w + cv1.w;

    uint4 w;
    w.x = (uint)f2bf(a[0]) | ((uint)f2bf(a[1]) << 16);
    w.y = (uint)f2bf(a[2]) | ((uint)f2bf(a[3]) << 16);
    w.z = (uint)f2bf(a[4]) | ((uint)f2bf(a[5]) << 16);
    w.w = (uint)f2bf(a[6]) | ((uint)f2bf(a[7]) << 16);
    *(uint4*)(tmpb + o) = w;
}

// ---- Kernel 7: out = tmp @ fW^T + fb  (64 rows/block, 512 thr, bf16 in) ---
__global__ __launch_bounds__(512) void fusion_kernel(
    const ushort* __restrict__ tmpb, const float* __restrict__ fW,
    const float* __restrict__ fb, float* __restrict__ out, int N)
{
    __shared__ float Wt[C][C + 1];   // 16.25 KB, Wt[k][j] = fW[j*C+k]
    __shared__ float tl[64][C];      // 16 KB
    int t = threadIdx.x;
    #pragma unroll
    for (int i = 0; i < 8; ++i) {
        int idx = t + i * 512;
        Wt[idx & 63][idx >> 6] = fW[idx];
    }
    int n0 = blockIdx.x * 64;
    {
        int rr = t >> 3, cs = (t & 7) << 3;   // 512 thr x 8 ch = 64 rows
        int n = n0 + rr;
        uint4 u = (n < N) ? *(const uint4*)(tmpb + (size_t)n * C + cs)
                          : make_uint4(0u, 0u, 0u, 0u);
        tl[rr][cs + 0] = __uint_as_float(u.x << 16);
        tl[rr][cs + 1] = __uint_as_float(u.x & 0xffff0000u);
        tl[rr][cs + 2] = __uint_as_float(u.y << 16);
        tl[rr][cs + 3] = __uint_as_float(u.y & 0xffff0000u);
        tl[rr][cs + 4] = __uint_as_float(u.z << 16);
        tl[rr][cs + 5] = __uint_as_float(u.z & 0xffff0000u);
        tl[rr][cs + 6] = __uint_as_float(u.w << 16);
        tl[rr][cs + 7] = __uint_as_float(u.w & 0xffff0000u);
    }
    __syncthreads();

    int j = t & 63, rb = (t >> 6) * 8;        // 8 waves x 8 rows = 64 rows
    float bj = fb[j];
    float acc[8] = {bj, bj, bj, bj, bj, bj, bj, bj};
    for (int k = 0; k < C; ++k) {
        float w = Wt[k][j];
        #pragma unroll
        for (int q = 0; q < 8; ++q) acc[q] = fmaf(tl[rb + q][k], w, acc[q]);
    }
    #pragma unroll
    for (int q = 0; q < 8; ++q) {
        int n = n0 + rb + q;
        if (n < N) out[(size_t)n * C + j] = acc[q];
    }
}

extern "C" void kernel_launch(void* const* d_in, const int* in_sizes, int n_in,
                              void* d_out, int out_size, void* d_ws, size_t ws_size,
                              hipStream_t stream)
{
    const float* X        = (const float*)d_in[0];
    const int*   ei       = (const int*)d_in[1];
    const float* ew       = (const float*)d_in[2];
    const float* node_emb = (const float*)d_in[3];
    const float* com_emb  = (const float*)d_in[4];
    const float* cw       = (const float*)d_in[5];
    const float* w_ih_f   = (const float*)d_in[6];
    const float* b_ih_f   = (const float*)d_in[7];
    const float* b_hh_f   = (const float*)d_in[8];
    const float* w_ih_b   = (const float*)d_in[9];
    const float* b_ih_b   = (const float*)d_in[10];
    const float* b_hh_b   = (const float*)d_in[11];
    const float* fW       = (const float*)d_in[12];
    const float* fb       = (const float*)d_in[13];
    float* out = (float*)d_out;

    const int N = in_sizes[0] / C;
    const int E = in_sizes[2];
    const int* row = ei;               // edge_index[0]
    const int* col = ei + E;           // edge_index[1]
    const int nbuck = (N + BN - 1) / BN;        // 782 (<= 1024 by design)
    const int epb = (E + NPART - 1) / NPART;    // 3125 <= EPB_CAP

    // ---- workspace layout ----
    // [W][dinv][btot][seg][payload2: E*8][big: max(E*8 + hist, N*C*2)]
    char* wsb = (char*)d_ws;
    size_t o = 0;
    auto alloc = [&](size_t bytes) { void* p = wsb + o; o = (o + bytes + 15) & ~(size_t)15; return p; };
    float* W        = (float*)alloc((size_t)C * C * sizeof(float));      // 16 KB
    float* dinv     = (float*)alloc((size_t)N * sizeof(float));          // 400 KB
    int*   btot     = (int*)  alloc((size_t)(nbuck + 1) * sizeof(int));  // 3 KB
    int2*  seg      = (int2*) alloc((size_t)N * sizeof(int2));           // 800 KB
    int2*  payload2 = (int2*) alloc((size_t)E * sizeof(int2));           // 12.8 MB
    size_t big_bytes_a = (size_t)E * 8 + (size_t)NPART * nbuck * 4;      // payload+hist
    size_t big_bytes_b = (size_t)N * C * 2;                              // tmpb
    char*  big      = (char*)alloc(big_bytes_a > big_bytes_b ? big_bytes_a : big_bytes_b);
    int2*  payload  = (int2*)big;
    int*   hist     = (int*)(big + (size_t)E * 8);
    ushort* tmpb    = (ushort*)big;
    ushort* Xw      = (ushort*)out;    // d_out holds bf16 Xw' until fusion overwrites

    hist_lstm_kernel<<<NPART + (C * C) / 256, 256, 0, stream>>>(
        col, hist, E, nbuck, epb,
        cw, w_ih_f, b_ih_f, b_hh_f, w_ih_b, b_ih_b, b_hh_b, W);

    scan_blocks_kernel<<<nbuck, NPART, 0, stream>>>(hist, btot, nbuck);

    partition_kernel<<<NPART, 512, 0, stream>>>(
        row, col, ew, hist, btot, payload, E, nbuck, epb);

    sort_bucket_kernel<<<nbuck, 512, 0, stream>>>(
        payload, btot, payload2, dinv, seg, N, nbuck);

    gemm_xw_kernel<<<(N + 63) / 64, 512, 0, stream>>>(X, W, dinv, Xw, N);

    reduce_kernel<<<(N * 8 + 255) / 256, 256, 0, stream>>>(
        seg, payload2, Xw, dinv, node_emb, com_emb, tmpb, N);

    fusion_kernel<<<(N + 63) / 64, 512, 0, stream>>>(tmpb, fW, fb, out, N);
}

// Round 13
// 151.481 us; speedup vs baseline: 1.0116x; 1.0116x over previous
//
#include <hip/hip_runtime.h>
#include <math.h>

#define C 64
#define BN 128              // nodes per destination bucket
#define BSHIFT 7            // log2(BN)
#define NPART 512           // partition blocks
#define EPB_CAP 3200        // LDS staging capacity per partition block
#define SCAP 4096           // LDS staging capacity per sort bucket (mean 2046, ~45 sigma)
#define RMASK ((1 << 20) - 1)

typedef unsigned int uint;
typedef unsigned short ushort;

__device__ __forceinline__ float sigf(float x) { return 1.0f / (1.0f + __expf(-x)); }

// round-to-nearest-even f32 -> bf16 bits (values are finite, no NaN handling)
__device__ __forceinline__ ushort f2bf(float f) {
    uint u = __float_as_uint(f);
    return (ushort)((u + 0x7fffu + ((u >> 16) & 1u)) >> 16);
}

// fma 8 packed bf16 (uint4) into acc[8]
__device__ __forceinline__ void bf8fma(uint4 u, float nn, float* a) {
    a[0] = fmaf(__uint_as_float(u.x << 16),          nn, a[0]);
    a[1] = fmaf(__uint_as_float(u.x & 0xffff0000u),  nn, a[1]);
    a[2] = fmaf(__uint_as_float(u.y << 16),          nn, a[2]);
    a[3] = fmaf(__uint_as_float(u.y & 0xffff0000u),  nn, a[3]);
    a[4] = fmaf(__uint_as_float(u.z << 16),          nn, a[4]);
    a[5] = fmaf(__uint_as_float(u.z & 0xffff0000u),  nn, a[5]);
    a[6] = fmaf(__uint_as_float(u.w << 16),          nn, a[6]);
    a[7] = fmaf(__uint_as_float(u.w & 0xffff0000u),  nn, a[7]);
}

// in-LDS spine: bbl[0..nbuck-1] = exclusive scan of btot (512 threads, 2/thread)
__device__ __forceinline__ void spine_scan(
    const int* __restrict__ btot, int* bbl, int* wsum, int nbuck, int t)
{
    int lane = t & 63, wid = t >> 6;
    int i0 = 2 * t, i1 = 2 * t + 1;
    int v0 = (i0 < nbuck) ? btot[i0] : 0;
    int v1 = (i1 < nbuck) ? btot[i1] : 0;
    int s = v0 + v1;
    int x = s;
    #pragma unroll
    for (int d = 1; d < 64; d <<= 1) {
        int y = __shfl_up(x, d, 64);
        if (lane >= d) x += y;
    }
    if (lane == 63) wsum[wid] = x;
    __syncthreads();
    if (t == 0) {
        int run = 0;
        #pragma unroll
        for (int w = 0; w < 8; ++w) { int z = wsum[w]; wsum[w] = run; run += z; }
    }
    __syncthreads();
    int excl = x - s + wsum[wid];
    bbl[i0] = excl;
    bbl[i1] = excl + v0;
}

// ---- Kernel 1: hist (blocks < NPART) + LSTM weight (blocks >= NPART) ------
__global__ __launch_bounds__(256) void hist_lstm_kernel(
    const int* __restrict__ col, int* __restrict__ hist,
    int E, int nbuck, int epb,
    const float* __restrict__ cw,
    const float* __restrict__ wf, const float* __restrict__ bif, const float* __restrict__ bhf,
    const float* __restrict__ wb, const float* __restrict__ bib, const float* __restrict__ bhb,
    float* __restrict__ W)
{
    int b = blockIdx.x, t = threadIdx.x;

    if (b >= NPART) {
        int tid = (b - NPART) * 256 + t;       // 0..4095
        int r = tid >> 6, c = tid & 63;
        const float* x = cw + r * C;
        const float* f_i = wf + (0 * C + c) * C;
        const float* f_g = wf + (2 * C + c) * C;
        const float* f_o = wf + (3 * C + c) * C;
        const float* b_i = wb + (0 * C + c) * C;
        const float* b_g = wb + (2 * C + c) * C;
        const float* b_o = wb + (3 * C + c) * C;

        float zif = 0.f, zgf = 0.f, zof = 0.f, zib = 0.f, zgb = 0.f, zob = 0.f;
        #pragma unroll
        for (int k = 0; k < C; ++k) {
            float xv = x[k];
            zif = fmaf(xv, f_i[k], zif);
            zgf = fmaf(xv, f_g[k], zgf);
            zof = fmaf(xv, f_o[k], zof);
            zib = fmaf(xv, b_i[k], zib);
            zgb = fmaf(xv, b_g[k], zgb);
            zob = fmaf(xv, b_o[k], zob);
        }
        zif += bif[0 * C + c] + bhf[0 * C + c];
        zgf += bif[2 * C + c] + bhf[2 * C + c];
        zof += bif[3 * C + c] + bhf[3 * C + c];
        zib += bib[0 * C + c] + bhb[0 * C + c];
        zgb += bib[2 * C + c] + bhb[2 * C + c];
        zob += bib[3 * C + c] + bhb[3 * C + c];

        float cf = sigf(zif) * tanhf(zgf);
        float hf = sigf(zof) * tanhf(cf);
        float cb = sigf(zib) * tanhf(zgb);
        float hb = sigf(zob) * tanhf(cb);
        W[tid] = fmaxf(hf, hb);
        return;
    }

    __shared__ int h[1024];
    for (int i = t; i < nbuck; i += 256) h[i] = 0;
    __syncthreads();
    int base = b * epb;
    int end = min(base + epb, E);
    for (int e = base + t; e < end; e += 256)
        atomicAdd(&h[col[e] >> BSHIFT], 1);
    __syncthreads();
    for (int i = t; i < nbuck; i += 256) hist[b * nbuck + i] = h[i];
}

// ---- Kernel 2: per-bucket exclusive scan over blocks (parallel) -----------
// hist[b][k] becomes exclusive prefix (over blocks) for bucket k; btot[k]=total.
__global__ __launch_bounds__(512) void scan_blocks_kernel(
    int* __restrict__ hist, int* __restrict__ btot, int nbuck)
{
    __shared__ int wsum[8];
    int k = blockIdx.x;
    int b = threadIdx.x;
    int v = hist[b * nbuck + k];
    int lane = b & 63, wid = b >> 6;
    int x = v;
    #pragma unroll
    for (int d = 1; d < 64; d <<= 1) {
        int y = __shfl_up(x, d, 64);
        if (lane >= d) x += y;
    }
    if (lane == 63) wsum[wid] = x;
    __syncthreads();
    if (b == 0) {
        int run = 0;
        #pragma unroll
        for (int w = 0; w < 8; ++w) { int z = wsum[w]; wsum[w] = run; run += z; }
    }
    __syncthreads();
    int excl = x - v + wsum[wid];
    hist[b * nbuck + k] = excl;
    if (b == NPART - 1) btot[k] = excl + v;
}

// ---- Kernel 3: partition — no recount (bins derived from scanned hist) ----
__global__ __launch_bounds__(512) void partition_kernel(
    const int* __restrict__ row, const int* __restrict__ col,
    const float* __restrict__ ew, const int* __restrict__ hist,
    const int* __restrict__ btot, int2* __restrict__ payload,
    int E, int nbuck, int epb)
{
    __shared__ int bins[1024];
    __shared__ int base[1024];
    __shared__ int cur[1024];
    __shared__ int hbase[1024];
    __shared__ int bbl[1024];
    __shared__ int2 lpay[EPB_CAP];      // 25.6 KB
    __shared__ ushort karr[EPB_CAP];    // 6.4 KB
    __shared__ int wsum[8];

    int t = threadIdx.x, b = blockIdx.x;
    int lane = t & 63, wid = t >> 6;

    spine_scan(btot, bbl, wsum, nbuck, t);

    // bins[k] = this block's count for bucket k, derived from scanned hist
    for (int i = t; i < 1024; i += 512) {
        int hb = (i < nbuck) ? hist[b * nbuck + i] : 0;
        int hn = 0;
        if (i < nbuck)
            hn = (b < NPART - 1) ? hist[(b + 1) * nbuck + i] : btot[i];
        hbase[i] = hb;
        bins[i] = hn - hb;
    }
    __syncthreads();

    // local exclusive scan of bins
    {
        int a = bins[2 * t], b2 = bins[2 * t + 1];
        int s = a + b2;
        int x = s;
        #pragma unroll
        for (int d = 1; d < 64; d <<= 1) {
            int y = __shfl_up(x, d, 64);
            if (lane >= d) x += y;
        }
        if (lane == 63) wsum[wid] = x;
        __syncthreads();
        if (t == 0) {
            int run = 0;
            #pragma unroll
            for (int w = 0; w < 8; ++w) { int z = wsum[w]; wsum[w] = run; run += z; }
        }
        __syncthreads();
        int excl = x - s + wsum[wid];
        base[2 * t] = excl;
        base[2 * t + 1] = excl + a;
        cur[2 * t] = excl;
        cur[2 * t + 1] = excl + a;
    }
    __syncthreads();

    int e0 = b * epb;
    int e1 = min(e0 + epb, E);
    for (int e = e0 + t; e < e1; e += 512) {
        int c = col[e];
        int k = c >> BSHIFT;
        int pos = atomicAdd(&cur[k], 1);
        lpay[pos] = make_int2(row[e] | ((c & (BN - 1)) << 20),
                              __float_as_int(ew[e]));
        karr[pos] = (ushort)k;
    }
    __syncthreads();

    int tot = e1 - e0;
    for (int i = t; i < tot; i += 512) {
        int k = karr[i];
        int dst = bbl[k] + hbase[k] + (i - base[k]);
        payload[dst] = lpay[i];
    }
}

// ---- Kernel 4: deg_bins — per-bucket weighted degree -> dinv, bin counts --
__global__ __launch_bounds__(512) void deg_bins_kernel(
    const int2* __restrict__ payload, const int* __restrict__ btot,
    float* __restrict__ dinv, int* __restrict__ binsg, int N, int nbuck)
{
    __shared__ int bbl[1024];
    __shared__ int wsum[8];
    __shared__ int bin[BN];
    __shared__ float degl[BN];
    int t = threadIdx.x, k = blockIdx.x;

    spine_scan(btot, bbl, wsum, nbuck, t);
    if (t < BN) { bin[t] = 0; degl[t] = 0.f; }
    __syncthreads();

    int e0 = bbl[k], e1 = e0 + btot[k];
    for (int e = e0 + t; e < e1; e += 512) {
        int2 p = payload[e];
        int ld = p.x >> 20;
        atomicAdd(&bin[ld], 1);
        atomicAdd(&degl[ld], __int_as_float(p.y));
    }
    __syncthreads();

    if (t < BN) {
        int n = k * BN + t;
        if (n < N) dinv[n] = rsqrtf(degl[t] + 1.0f);   // +1 self-loop weight
        binsg[k * BN + t] = bin[t];
    }
}

// ---- Kernel 5: Xw' = bf16( dinv ⊙ (X @ W) )  (64 rows/block, 512 thr) -----
__global__ __launch_bounds__(512) void gemm_xw_kernel(
    const float* __restrict__ X, const float* __restrict__ W,
    const float* __restrict__ dinv, ushort* __restrict__ Y, int N)
{
    __shared__ float Wl[C * C];         // 16 KB
    __shared__ float xl[64][C];         // 16 KB
    int t = threadIdx.x;
    #pragma unroll
    for (int i = 0; i < 2; ++i)
        *(float4*)(Wl + 4 * (t + i * 512)) = *(const float4*)(W + 4 * (t + i * 512));

    int n0 = blockIdx.x * 64;
    #pragma unroll
    for (int i = 0; i < 2; ++i) {
        int idx = t + i * 512;            // 0..1023 : (row, float4-group)
        int rr = idx >> 4, cc = (idx & 15) << 2;
        int n = n0 + rr;
        float4 v = (n < N) ? *(const float4*)(X + (size_t)n * C + cc)
                           : make_float4(0.f, 0.f, 0.f, 0.f);
        *(float4*)(&xl[rr][cc]) = v;
    }
    __syncthreads();

    int c = t & 63, rb = (t >> 6) * 8;    // 8 waves x 8 rows = 64 rows
    float acc[8] = {0.f, 0.f, 0.f, 0.f, 0.f, 0.f, 0.f, 0.f};
    for (int k = 0; k < C; ++k) {
        float w = Wl[k * C + c];
        #pragma unroll
        for (int q = 0; q < 8; ++q) acc[q] = fmaf(xl[rb + q][k], w, acc[q]);
    }
    #pragma unroll
    for (int q = 0; q < 8; ++q) {
        int n = n0 + rb + q;
        if (n < N) Y[(size_t)n * C + c] = f2bf(acc[q] * dinv[n]);  // fold dinv[src]
    }
}

// ---- Kernel 6: sort_reduce — LDS counting sort + gather-reduce fused ------
// Per bucket: scatter node-sorted {row, w*dinv[dst]} into LDS, then for each
// node (8 lanes, uint4 gathers, 4 edges in flight) accumulate and write
// tmp[n] = bf16( ne + ce + dinv[n]*Xw'[n] + sum pn * Xw'[src] ).
__global__ __launch_bounds__(512) void sort_reduce_kernel(
    const int2* __restrict__ payload, const int* __restrict__ btot,
    const int* __restrict__ binsg, const float* __restrict__ dinv,
    const ushort* __restrict__ Xw,
    const float* __restrict__ ne, const float* __restrict__ ce,
    ushort* __restrict__ tmpb, int N, int nbuck)
{
    __shared__ int bbl[1024];
    __shared__ int wsum[8];
    __shared__ int bin[BN];
    __shared__ int bbase[BN];
    __shared__ int cur[BN];
    __shared__ float dinvl[BN];
    __shared__ int2 spay[SCAP];         // 32 KB
    int t = threadIdx.x, k = blockIdx.x;

    spine_scan(btot, bbl, wsum, nbuck, t);

    if (t < BN) {
        int n = k * BN + t;
        bin[t] = binsg[k * BN + t];
        dinvl[t] = (n < N) ? dinv[n] : 0.f;
    }
    __syncthreads();

    // exclusive scan of bin[0..127] in wave 0 (2 bins per lane)
    if (t < 64) {
        int a = bin[2 * t], b2 = bin[2 * t + 1];
        int s = a + b2;
        int x = s;
        #pragma unroll
        for (int d = 1; d < 64; d <<= 1) {
            int y = __shfl_up(x, d, 64);
            if (t >= d) x += y;
        }
        int excl = x - s;
        bbase[2 * t] = excl;
        bbase[2 * t + 1] = excl + a;
    }
    __syncthreads();
    if (t < BN) cur[t] = bbase[t];
    __syncthreads();

    int e0 = bbl[k];
    int tot = btot[k];
    bool fits = (tot <= SCAP);

    if (fits) {
        for (int e = e0 + t; e < e0 + tot; e += 512) {
            int2 p = payload[e];
            int ld = p.x >> 20;
            int pos = atomicAdd(&cur[ld], 1);
            spay[pos] = make_int2(p.x & RMASK,
                                  __float_as_int(__int_as_float(p.y) * dinvl[ld]));
        }
    }
    __syncthreads();

    // ---- reduce phase: 2 passes x 64 nodes, 8 lanes/node ----
    int lg = t >> 3;                      // node group 0..63
    int cs = (t & 7) << 3;                // channel offset (8 channels/lane)
    #pragma unroll
    for (int pass = 0; pass < 2; ++pass) {
        int ln = lg + pass * 64;          // local node 0..127
        int n = k * BN + ln;
        if (n >= N) continue;

        float a[8] = {0.f, 0.f, 0.f, 0.f, 0.f, 0.f, 0.f, 0.f};
        if (fits) {
            int j = bbase[ln], cnt = bin[ln];
            while (cnt >= 4) {
                int2 p0 = spay[j];
                int2 p1 = spay[j + 1];
                int2 p2 = spay[j + 2];
                int2 p3 = spay[j + 3];
                uint4 u0 = *(const uint4*)(Xw + (size_t)p0.x * C + cs);
                uint4 u1 = *(const uint4*)(Xw + (size_t)p1.x * C + cs);
                uint4 u2 = *(const uint4*)(Xw + (size_t)p2.x * C + cs);
                uint4 u3 = *(const uint4*)(Xw + (size_t)p3.x * C + cs);
                bf8fma(u0, __int_as_float(p0.y), a);
                bf8fma(u1, __int_as_float(p1.y), a);
                bf8fma(u2, __int_as_float(p2.y), a);
                bf8fma(u3, __int_as_float(p3.y), a);
                j += 4; cnt -= 4;
            }
            while (cnt > 0) {
                int2 pl = spay[j];
                uint4 u = *(const uint4*)(Xw + (size_t)pl.x * C + cs);
                bf8fma(u, __int_as_float(pl.y), a);
                ++j; --cnt;
            }
        } else {
            // correctness fallback (tot > SCAP never occurs for this data):
            // filter-scan the whole bucket from global payload.
            for (int e = e0; e < e0 + tot; ++e) {
                int2 p = payload[e];
                if ((p.x >> 20) == ln) {
                    float nn = __int_as_float(p.y) * dinvl[ln];
                    uint4 u = *(const uint4*)(Xw + (size_t)(p.x & RMASK) * C + cs);
                    bf8fma(u, nn, a);
                }
            }
        }

        float di = dinvl[ln];
        size_t o = (size_t)n * C + cs;
        uint4 ux = *(const uint4*)(Xw + o);     // Xw' = dinv[n]*(X@W)[n]
        bf8fma(ux, di, a);
        const float4 nv0 = *(const float4*)(ne + o);
        const float4 nv1 = *(const float4*)(ne + o + 4);
        const float4 cv0 = *(const float4*)(ce + o);
        const float4 cv1 = *(const float4*)(ce + o + 4);
        a[0] += nv0.x + cv0.x;  a[1] += nv0.y + cv0.y;
        a[2] += nv0.z + cv0.z;  a[3] += nv0.w + cv0.w;
        a[4] += nv1.x + cv1.x;  a[5] += nv1.y + cv1.y;
        a[6] += nv1.z + cv1.z;  a[7] += nv1.w + cv1.w;

        uint4 w;
        w.x = (uint)f2bf(a[0]) | ((uint)f2bf(a[1]) << 16);
        w.y = (uint)f2bf(a[2]) | ((uint)f2bf(a[3]) << 16);
        w.z = (uint)f2bf(a[4]) | ((uint)f2bf(a[5]) << 16);
        w.w = (uint)f2bf(a[6]) | ((uint)f2bf(a[7]) << 16);
        *(uint4*)(tmpb + o) = w;
    }
}

// ---- Kernel 7: out = tmp @ fW^T + fb  (64 rows/block, 512 thr, bf16 in) ---
__global__ __launch_bounds__(512) void fusion_kernel(
    const ushort* __restrict__ tmpb, const float* __restrict__ fW,
    const float* __restrict__ fb, float* __restrict__ out, int N)
{
    __shared__ float Wt[C][C + 1];   // 16.25 KB, Wt[k][j] = fW[j*C+k]
    __shared__ float tl[64][C];      // 16 KB
    int t = threadIdx.x;
    #pragma unroll
    for (int i = 0; i < 8; ++i) {
        int idx = t + i * 512;
        Wt[idx & 63][idx >> 6] = fW[idx];
    }
    int n0 = blockIdx.x * 64;
    {
        int rr = t >> 3, cs = (t & 7) << 3;   // 512 thr x 8 ch = 64 rows
        int n = n0 + rr;
        uint4 u = (n < N) ? *(const uint4*)(tmpb + (size_t)n * C + cs)
                          : make_uint4(0u, 0u, 0u, 0u);
        tl[rr][cs + 0] = __uint_as_float(u.x << 16);
        tl[rr][cs + 1] = __uint_as_float(u.x & 0xffff0000u);
        tl[rr][cs + 2] = __uint_as_float(u.y << 16);
        tl[rr][cs + 3] = __uint_as_float(u.y & 0xffff0000u);
        tl[rr][cs + 4] = __uint_as_float(u.z << 16);
        tl[rr][cs + 5] = __uint_as_float(u.z & 0xffff0000u);
        tl[rr][cs + 6] = __uint_as_float(u.w << 16);
        tl[rr][cs + 7] = __uint_as_float(u.w & 0xffff0000u);
    }
    __syncthreads();

    int j = t & 63, rb = (t >> 6) * 8;        // 8 waves x 8 rows = 64 rows
    float bj = fb[j];
    float acc[8] = {bj, bj, bj, bj, bj, bj, bj, bj};
    for (int k = 0; k < C; ++k) {
        float w = Wt[k][j];
        #pragma unroll
        for (int q = 0; q < 8; ++q) acc[q] = fmaf(tl[rb + q][k], w, acc[q]);
    }
    #pragma unroll
    for (int q = 0; q < 8; ++q) {
        int n = n0 + rb + q;
        if (n < N) out[(size_t)n * C + j] = acc[q];
    }
}

extern "C" void kernel_launch(void* const* d_in, const int* in_sizes, int n_in,
                              void* d_out, int out_size, void* d_ws, size_t ws_size,
                              hipStream_t stream)
{
    const float* X        = (const float*)d_in[0];
    const int*   ei       = (const int*)d_in[1];
    const float* ew       = (const float*)d_in[2];
    const float* node_emb = (const float*)d_in[3];
    const float* com_emb  = (const float*)d_in[4];
    const float* cw       = (const float*)d_in[5];
    const float* w_ih_f   = (const float*)d_in[6];
    const float* b_ih_f   = (const float*)d_in[7];
    const float* b_hh_f   = (const float*)d_in[8];
    const float* w_ih_b   = (const float*)d_in[9];
    const float* b_ih_b   = (const float*)d_in[10];
    const float* b_hh_b   = (const float*)d_in[11];
    const float* fW       = (const float*)d_in[12];
    const float* fb       = (const float*)d_in[13];
    float* out = (float*)d_out;

    const int N = in_sizes[0] / C;
    const int E = in_sizes[2];
    const int* row = ei;               // edge_index[0]
    const int* col = ei + E;           // edge_index[1]
    const int nbuck = (N + BN - 1) / BN;        // 782 (<= 1024 by design)
    const int epb = (E + NPART - 1) / NPART;    // 3125 <= EPB_CAP

    // ---- workspace layout ----
    // [W][dinv][btot][binsg][big: payload E*8 | hist | tmpb]
    // payload + tmpb are simultaneously live in sort_reduce -> disjoint.
    char* wsb = (char*)d_ws;
    size_t o = 0;
    auto alloc = [&](size_t bytes) { void* p = wsb + o; o = (o + bytes + 15) & ~(size_t)15; return p; };
    float* W     = (float*)alloc((size_t)C * C * sizeof(float));        // 16 KB
    float* dinv  = (float*)alloc((size_t)N * sizeof(float));            // 400 KB
    int*   btot  = (int*)  alloc((size_t)(nbuck + 1) * sizeof(int));    // 3 KB
    int*   binsg = (int*)  alloc((size_t)nbuck * BN * sizeof(int));     // 400 KB
    int2*  payload = (int2*)alloc((size_t)E * sizeof(int2));            // 12.8 MB
    int*   hist  = (int*)  alloc((size_t)NPART * nbuck * sizeof(int));  // 1.6 MB
    ushort* tmpb = (ushort*)alloc((size_t)N * C * sizeof(ushort));      // 12.8 MB
    ushort* Xw   = (ushort*)out;   // d_out holds bf16 Xw' until fusion overwrites

    hist_lstm_kernel<<<NPART + (C * C) / 256, 256, 0, stream>>>(
        col, hist, E, nbuck, epb,
        cw, w_ih_f, b_ih_f, b_hh_f, w_ih_b, b_ih_b, b_hh_b, W);

    scan_blocks_kernel<<<nbuck, NPART, 0, stream>>>(hist, btot, nbuck);

    partition_kernel<<<NPART, 512, 0, stream>>>(
        row, col, ew, hist, btot, payload, E, nbuck, epb);

    deg_bins_kernel<<<nbuck, 512, 0, stream>>>(
        payload, btot, dinv, binsg, N, nbuck);

    gemm_xw_kernel<<<(N + 63) / 64, 512, 0, stream>>>(X, W, dinv, Xw, N);

    sort_reduce_kernel<<<nbuck, 512, 0, stream>>>(
        payload, btot, binsg, dinv, Xw, node_emb, com_emb, tmpb, N, nbuck);

    fusion_kernel<<<(N + 63) / 64, 512, 0, stream>>>(tmpb, fW, fb, out, N);
}